// Round 6
// baseline (286.966 us; speedup 1.0000x reference)
//
#include <hip/hip_runtime.h>
#include <cstdint>
#include <cstddef>

#define NN 50000
#define NE 800000
#define GRAPHS 512
#define NBK 782                               // ceil(50000/64) buckets of 64 nodes

typedef __attribute__((ext_vector_type(8))) short bf16x8;
typedef __attribute__((ext_vector_type(4))) float f32x4;

__device__ __forceinline__ unsigned short f2bf(float f) {
  union { float f; unsigned u; } v; v.f = f;
  unsigned r = v.u + 0x7FFF + ((v.u >> 16) & 1);   // RNE
  return (unsigned short)(r >> 16);
}
__device__ __forceinline__ float bf2f(unsigned short h) {
  union { unsigned u; float f; } v; v.u = ((unsigned)h) << 16;
  return v.f;
}

__global__ __launch_bounds__(256) void zero_kernel(int* __restrict__ p, int n) {
  int i = blockIdx.x * 256 + threadIdx.x;
  if (i < n) p[i] = 0;
}

// ============ hierarchical CSR build (bucket = 64 consecutive nodes) ============

__global__ __launch_bounds__(256) void bcount_kernel(const int* __restrict__ dst,
                                                     int* __restrict__ bcnt) {
  __shared__ int hist[NBK];
  const int t = threadIdx.x;
  for (int b = t; b < NBK; b += 256) hist[b] = 0;
  __syncthreads();
  const int e0 = blockIdx.x * 2048;
  #pragma unroll
  for (int i = 0; i < 8; ++i) {
    int e = e0 + i * 256 + t;
    if (e < NE) atomicAdd(&hist[dst[e] >> 6], 1);
  }
  __syncthreads();
  for (int b = t; b < NBK; b += 256) {
    int c = hist[b];
    if (c) atomicAdd(&bcnt[b], c);
  }
}

__global__ __launch_bounds__(1024) void bscan_kernel(const int* __restrict__ bcnt,
                                                     int* __restrict__ bbase,
                                                     int* __restrict__ bcur) {
  __shared__ int sd[1024];
  const int t = threadIdx.x;
  int v = (t < NBK) ? bcnt[t] : 0;
  sd[t] = v;
  __syncthreads();
  for (int off = 1; off < 1024; off <<= 1) {
    int u = (t >= off) ? sd[t - off] : 0;
    __syncthreads();
    sd[t] += u;
    __syncthreads();
  }
  if (t < NBK) { int ex = sd[t] - v; bbase[t] = ex; bcur[t] = ex; }
  if (t == NBK - 1) bbase[NBK] = sd[t];      // = NE
}

// packed edge: (dst&63)<<17 | src   (src < 2^17)
__global__ __launch_bounds__(256) void bin_kernel(const int* __restrict__ src,
                                                  const int* __restrict__ dst,
                                                  int* __restrict__ bcur,
                                                  unsigned* __restrict__ ebuf) {
  __shared__ int hist[NBK];
  __shared__ int base[NBK];
  __shared__ int lcur[NBK];
  const int t = threadIdx.x;
  for (int b = t; b < NBK; b += 256) { hist[b] = 0; lcur[b] = 0; }
  __syncthreads();
  const int e0 = blockIdx.x * 4096;
  unsigned pk[16]; int bk[16];
  #pragma unroll
  for (int i = 0; i < 16; ++i) {
    int e = e0 + i * 256 + t;
    if (e < NE) {
      int s = src[e], d = dst[e];
      bk[i] = d >> 6;
      pk[i] = ((unsigned)(d & 63) << 17) | (unsigned)s;
      atomicAdd(&hist[bk[i]], 1);
    } else bk[i] = -1;
  }
  __syncthreads();
  for (int b = t; b < NBK; b += 256) {
    int c = hist[b];
    if (c) base[b] = atomicAdd(&bcur[b], c);
  }
  __syncthreads();
  #pragma unroll
  for (int i = 0; i < 16; ++i) {
    if (bk[i] >= 0) {
      int r = atomicAdd(&lcur[bk[i]], 1);
      ebuf[base[bk[i]] + r] = pk[i];
    }
  }
}

__global__ __launch_bounds__(256) void bucket_csr_kernel(const unsigned* __restrict__ ebuf,
                                                         const int* __restrict__ bbase,
                                                         int* __restrict__ row_start,
                                                         int* __restrict__ ssrc) {
  __shared__ int ehist[64];
  __shared__ int sd[64];
  __shared__ int ecur[64];
  const int t = threadIdx.x;
  const int b = blockIdx.x;
  const int n0 = b << 6;
  const int e0 = bbase[b], e1 = bbase[b + 1];
  if (t < 64) ehist[t] = 0;
  __syncthreads();
  for (int e = e0 + t; e < e1; e += 256)
    atomicAdd(&ehist[ebuf[e] >> 17], 1);
  __syncthreads();
  if (t < 64) sd[t] = ehist[t];
  __syncthreads();
  for (int off = 1; off < 64; off <<= 1) {
    int u = (t >= off && t < 64) ? sd[t - off] : 0;
    __syncthreads();
    if (t < 64) sd[t] += u;
    __syncthreads();
  }
  if (t < 64) {
    int ex = e0 + sd[t] - ehist[t];
    ecur[t] = ex;
    if (n0 + t <= NN) row_start[n0 + t] = ex;
  }
  __syncthreads();
  for (int e = e0 + t; e < e1; e += 256) {
    unsigned ed = ebuf[e];
    int r = atomicAdd(&ecur[ed >> 17], 1);
    ssrc[r] = (int)(ed & 0x1FFFF);
  }
}

// ----------------- graph boundaries (batch is sorted) -----------------
__global__ __launch_bounds__(256) void bounds_kernel(const int* __restrict__ batch,
                                                     int* __restrict__ gstart) {
  int g = blockIdx.x * 256 + threadIdx.x;
  if (g > GRAPHS) return;
  int lo = 0, hi = NN;
  while (lo < hi) {
    int mid = (lo + hi) >> 1;
    if (batch[mid] < g) lo = mid + 1; else hi = mid;
  }
  gstart[g] = lo;
}

// ----------------- weight prep: transpose + cast to bf16, [col][k] -----------------
__global__ __launch_bounds__(256) void prep_w_kernel(
    const float* __restrict__ Wrel1, const float* __restrict__ Wroot1,
    const float* __restrict__ Wrel2, const float* __restrict__ Wroot2,
    const float* __restrict__ Wrel3, const float* __restrict__ Wroot3,
    unsigned short* __restrict__ Wt1, unsigned short* __restrict__ Wt2,
    unsigned short* __restrict__ Wt3) {
  int tid = blockIdx.x * 256 + threadIdx.x;
  int stride = gridDim.x * 256;
  for (int idx = tid; idx < 128 * 128; idx += stride) {
    int c = idx >> 7, k = idx & 127;
    Wt1[c * 128 + k] = f2bf(c < 64 ? Wrel1[k * 64 + c] : Wroot1[k * 64 + (c - 64)]);
  }
  for (int idx = tid; idx < 128 * 64; idx += stride) {
    int c = idx >> 6, k = idx & 63;
    Wt2[c * 64 + k] = f2bf(c < 64 ? Wrel2[k * 64 + c] : Wroot2[k * 64 + (c - 64)]);
    Wt3[c * 64 + k] = f2bf(c < 64 ? Wrel3[k * 64 + c] : Wroot3[k * 64 + (c - 64)]);
  }
}

// ----------------- layer-1 MFMA GEMM: [hW | buf] = x @ [Wrel | Wroot] ------------
__global__ __launch_bounds__(256) void gemm_mfma_l1(const float* __restrict__ h,
    const unsigned short* __restrict__ Wt,    // [128][128] bf16 (pre-transposed)
    const float* __restrict__ brel,
    unsigned short* __restrict__ hW,          // [NN][64] bf16 (rel result)
    float* __restrict__ buf) {                // [NN][64] f32  (root + bias)
  constexpr int K = 128;
  __shared__ __align__(16) unsigned short as[64 * K];
  __shared__ __align__(16) unsigned short bs[128 * K];
  constexpr int SEG = K / 8;
  const int t = threadIdx.x;
  const int row0 = blockIdx.x * 64;

  for (int idx = t; idx < 64 * SEG; idx += 256) {
    int r = idx / SEG, kq = idx % SEG;
    int node = row0 + r;
    float4 v0 = make_float4(0.f, 0.f, 0.f, 0.f), v1 = v0;
    if (node < NN) {
      const float* p = &h[(size_t)node * K + kq * 8];
      v0 = *(const float4*)p; v1 = *(const float4*)(p + 4);
    }
    uint4 p;
    p.x = f2bf(v0.x) | ((unsigned)f2bf(v0.y) << 16);
    p.y = f2bf(v0.z) | ((unsigned)f2bf(v0.w) << 16);
    p.z = f2bf(v1.x) | ((unsigned)f2bf(v1.y) << 16);
    p.w = f2bf(v1.z) | ((unsigned)f2bf(v1.w) << 16);
    int sidx = (r * K + kq * 8) ^ ((r & 7) << 3);
    *(uint4*)&as[sidx] = p;
  }
  for (int idx = t; idx < 128 * SEG; idx += 256) {
    int c = idx / SEG, kq = idx % SEG;
    uint4 v = *(const uint4*)&Wt[c * K + kq * 8];
    int sidx = (c * K + kq * 8) ^ ((c & 7) << 3);
    *(uint4*)&bs[sidx] = v;
  }
  __syncthreads();

  const int lane = t & 63, wave = t >> 6;
  const int li = lane & 15;
  const int kg = (lane >> 4) * 8;
  const int ar = wave * 16 + li;
  f32x4 acc[8];
  #pragma unroll
  for (int i = 0; i < 8; ++i) acc[i] = (f32x4){0.f, 0.f, 0.f, 0.f};

  #pragma unroll
  for (int k0 = 0; k0 < K; k0 += 32) {
    int ka = k0 + kg;
    bf16x8 a = *(bf16x8*)&as[(ar * K + ka) ^ ((ar & 7) << 3)];
    #pragma unroll
    for (int nb = 0; nb < 8; ++nb) {
      int bc = nb * 16 + li;
      bf16x8 b = *(bf16x8*)&bs[(bc * K + ka) ^ ((bc & 7) << 3)];
      acc[nb] = __builtin_amdgcn_mfma_f32_16x16x32_bf16(a, b, acc[nb], 0, 0, 0);
    }
  }

  const int orow = row0 + wave * 16 + (lane >> 4) * 4;
  #pragma unroll
  for (int nb = 0; nb < 4; ++nb) {
    #pragma unroll
    for (int r = 0; r < 4; ++r) {
      int node = orow + r;
      if (node < NN) hW[(size_t)node * 64 + nb * 16 + li] = f2bf(acc[nb][r]);
    }
  }
  #pragma unroll
  for (int nb = 4; nb < 8; ++nb) {
    float bb = brel[(nb - 4) * 16 + li];
    #pragma unroll
    for (int r = 0; r < 4; ++r) {
      int node = orow + r;
      if (node < NN) buf[(size_t)node * 64 + (nb - 4) * 16 + li] = acc[nb][r] + bb;
    }
  }
}

// ----- layers 2/3: fused gather + MFMA GEMM -----
// A-tile = relu(root[node] + sum_{e in CSR[node]} hW_prev[src_e]), then
// [hW | buf] = A @ [Wrel | Wroot].  K = 64.
__global__ __launch_bounds__(256) void gemm_agg_mfma(
    const float* __restrict__ root,           // [NN][64] f32 (prev root + bias)
    const unsigned short* __restrict__ hWp,   // [NN][64] bf16 (prev rel result)
    const int* __restrict__ rs, const int* __restrict__ ssrc,
    const unsigned short* __restrict__ Wt,    // [128][64] bf16
    const float* __restrict__ brel,
    unsigned short* __restrict__ hW,
    float* __restrict__ buf) {
  constexpr int K = 64;
  __shared__ __align__(16) unsigned short as[64 * K];
  __shared__ __align__(16) unsigned short bs[128 * K];
  const int t = threadIdx.x;
  const int row0 = blockIdx.x * 64;

  // stage B first (independent, issues early)
  for (int idx = t; idx < 128 * 8; idx += 256) {
    int c = idx >> 3, kq = idx & 7;
    uint4 v = *(const uint4*)&Wt[c * K + kq * 8];
    int sidx = (c * K + kq * 8) ^ ((c & 7) << 3);
    *(uint4*)&bs[sidx] = v;
  }

  // stage A: gather + root + relu + cast, 16 groups x 16 lanes
  const int grp = t >> 4, l16 = t & 15;
  #pragma unroll
  for (int i = 0; i < 4; ++i) {
    int r = grp + i * 16;
    int node = row0 + r;
    float4 v = make_float4(0.f, 0.f, 0.f, 0.f);
    if (node < NN) {
      v = *(const float4*)&root[(size_t)node * 64 + l16 * 4];
      int e0 = rs[node], e1 = rs[node + 1];
      for (int e = e0; e < e1; ++e) {
        int s = ssrc[e];
        ushort4 u = *(const ushort4*)&hWp[(size_t)s * 64 + l16 * 4];
        v.x += bf2f(u.x); v.y += bf2f(u.y);
        v.z += bf2f(u.z); v.w += bf2f(u.w);
      }
    }
    uint2 p;
    p.x = f2bf(fmaxf(v.x, 0.f)) | ((unsigned)f2bf(fmaxf(v.y, 0.f)) << 16);
    p.y = f2bf(fmaxf(v.z, 0.f)) | ((unsigned)f2bf(fmaxf(v.w, 0.f)) << 16);
    int sidx = (r * K + l16 * 4) ^ ((r & 7) << 3);
    *(uint2*)&as[sidx] = p;
  }
  __syncthreads();

  const int lane = t & 63, wave = t >> 6;
  const int li = lane & 15;
  const int kg = (lane >> 4) * 8;
  const int ar = wave * 16 + li;
  f32x4 acc[8];
  #pragma unroll
  for (int i = 0; i < 8; ++i) acc[i] = (f32x4){0.f, 0.f, 0.f, 0.f};

  #pragma unroll
  for (int k0 = 0; k0 < K; k0 += 32) {
    int ka = k0 + kg;
    bf16x8 a = *(bf16x8*)&as[(ar * K + ka) ^ ((ar & 7) << 3)];
    #pragma unroll
    for (int nb = 0; nb < 8; ++nb) {
      int bc = nb * 16 + li;
      bf16x8 b = *(bf16x8*)&bs[(bc * K + ka) ^ ((bc & 7) << 3)];
      acc[nb] = __builtin_amdgcn_mfma_f32_16x16x32_bf16(a, b, acc[nb], 0, 0, 0);
    }
  }

  const int orow = row0 + wave * 16 + (lane >> 4) * 4;
  #pragma unroll
  for (int nb = 0; nb < 4; ++nb) {
    #pragma unroll
    for (int r = 0; r < 4; ++r) {
      int node = orow + r;
      if (node < NN) hW[(size_t)node * 64 + nb * 16 + li] = f2bf(acc[nb][r]);
    }
  }
  #pragma unroll
  for (int nb = 4; nb < 8; ++nb) {
    float bb = brel[(nb - 4) * 16 + li];
    #pragma unroll
    for (int r = 0; r < 4; ++r) {
      int node = orow + r;
      if (node < NN) buf[(size_t)node * 64 + (nb - 4) * 16 + li] = acc[nb][r] + bb;
    }
  }
}

// ------- fused gather + mean-pool + MLP head: one block per graph -------
__global__ __launch_bounds__(256) void pool_head_kernel(
    const float* __restrict__ root,           // [NN][64] f32 (layer-3 root + bias)
    const unsigned short* __restrict__ hWp,   // [NN][64] bf16 (layer-3 rel result)
    const int* __restrict__ rs, const int* __restrict__ ssrc,
    const int* __restrict__ gstart,
    const float* __restrict__ Wfc1, const float* __restrict__ bfc1,
    const float* __restrict__ Wfc2, const float* __restrict__ bfc2,
    float* __restrict__ out) {
  __shared__ float ps[16][64];
  __shared__ float m[64];
  __shared__ float h1[32];
  const int g = blockIdx.x, t = threadIdx.x;
  const int grp = t >> 4, l16 = t & 15;
  const int s0 = gstart[g], s1 = gstart[g + 1];
  float4 acc = make_float4(0.f, 0.f, 0.f, 0.f);
  for (int i = s0 + grp; i < s1; i += 16) {
    float4 v = *(const float4*)&root[(size_t)i * 64 + l16 * 4];
    int e0 = rs[i], e1 = rs[i + 1];
    for (int e = e0; e < e1; ++e) {
      int s = ssrc[e];
      ushort4 u = *(const ushort4*)&hWp[(size_t)s * 64 + l16 * 4];
      v.x += bf2f(u.x); v.y += bf2f(u.y);
      v.z += bf2f(u.z); v.w += bf2f(u.w);
    }
    acc.x += fmaxf(v.x, 0.f); acc.y += fmaxf(v.y, 0.f);
    acc.z += fmaxf(v.z, 0.f); acc.w += fmaxf(v.w, 0.f);
  }
  *(float4*)&ps[grp][l16 * 4] = acc;
  __syncthreads();
  if (t < 64) {
    float s = 0.f;
    #pragma unroll
    for (int p = 0; p < 16; ++p) s += ps[p][t];
    m[t] = s / fmaxf((float)(s1 - s0), 1.0f);
  }
  __syncthreads();
  if (t < 32) {
    float a = bfc1[t];
    #pragma unroll
    for (int k = 0; k < 64; ++k) a += m[k] * Wfc1[k * 32 + t];
    h1[t] = fmaxf(a, 0.f);
  }
  __syncthreads();
  if (t == 0) {
    float o = bfc2[0];
    #pragma unroll
    for (int j = 0; j < 32; ++j) o += h1[j] * Wfc2[j];
    out[g] = o;
  }
}

extern "C" void kernel_launch(void* const* d_in, const int* in_sizes, int n_in,
                              void* d_out, int out_size, void* d_ws, size_t ws_size,
                              hipStream_t stream) {
  const float* x      = (const float*)d_in[0];
  const int*   ei     = (const int*)d_in[1];
  const int*   batch  = (const int*)d_in[2];
  const float* Wrel1  = (const float*)d_in[3];
  const float* brel1  = (const float*)d_in[4];
  const float* Wroot1 = (const float*)d_in[5];
  const float* Wrel2  = (const float*)d_in[6];
  const float* brel2  = (const float*)d_in[7];
  const float* Wroot2 = (const float*)d_in[8];
  const float* Wrel3  = (const float*)d_in[9];
  const float* brel3  = (const float*)d_in[10];
  const float* Wroot3 = (const float*)d_in[11];
  const float* Wfc1   = (const float*)d_in[12];
  const float* bfc1   = (const float*)d_in[13];
  const float* Wfc2   = (const float*)d_in[14];
  const float* bfc2   = (const float*)d_in[15];
  const int* src = ei;
  const int* dst = ei + NE;

  char* w = (char*)d_ws;
  auto alloc = [&](size_t bytes) -> char* {
    char* p = w; w += (bytes + 255) & ~(size_t)255; return p;
  };
  unsigned short* hWa = (unsigned short*)alloc((size_t)NN * 64 * 2);  // bf16
  unsigned short* hWb = (unsigned short*)alloc((size_t)NN * 64 * 2);  // bf16
  float* bufA   = (float*)alloc((size_t)NN * 64 * 4);
  float* bufB   = (float*)alloc((size_t)NN * 64 * 4);
  int*   rs     = (int*)alloc((size_t)(NN + 1) * 4);
  int*   ssrc   = (int*)alloc((size_t)NE * 4);
  int*   gstart = (int*)alloc((size_t)(GRAPHS + 1) * 4);
  int*   bcnt   = (int*)alloc((size_t)NBK * 4);
  int*   bbase  = (int*)alloc((size_t)(NBK + 1) * 4);
  int*   bcur   = (int*)alloc((size_t)NBK * 4);
  unsigned short* Wt1 = (unsigned short*)alloc((size_t)128 * 128 * 2);
  unsigned short* Wt2 = (unsigned short*)alloc((size_t)128 * 64 * 2);
  unsigned short* Wt3 = (unsigned short*)alloc((size_t)128 * 64 * 2);
  // ebuf aliases bufB: bufB is first written by gemm_agg layer-2, after bucket_csr
  unsigned* ebuf = (unsigned*)bufB;

  zero_kernel<<<(NBK + 255) / 256, 256, 0, stream>>>(bcnt, NBK);
  bcount_kernel<<<(NE + 2047) / 2048, 256, 0, stream>>>(dst, bcnt);
  bscan_kernel<<<1, 1024, 0, stream>>>(bcnt, bbase, bcur);
  bin_kernel<<<(NE + 4095) / 4096, 256, 0, stream>>>(src, dst, bcur, ebuf);
  bucket_csr_kernel<<<NBK, 256, 0, stream>>>(ebuf, bbase, rs, ssrc);
  bounds_kernel<<<(GRAPHS + 1 + 255) / 256, 256, 0, stream>>>(batch, gstart);
  prep_w_kernel<<<32, 256, 0, stream>>>(Wrel1, Wroot1, Wrel2, Wroot2, Wrel3, Wroot3,
                                        Wt1, Wt2, Wt3);

  const int ggrid = (NN + 63) / 64;          // 782

  // layer 1: hWa = x@Wrel1 (bf16), bufA = x@Wroot1 + b1
  gemm_mfma_l1<<<ggrid, 256, 0, stream>>>(x, Wt1, brel1, hWa, bufA);
  // layer 2: A = relu(bufA + gather(hWa)); hWb = A@Wrel2, bufB = A@Wroot2 + b2
  gemm_agg_mfma<<<ggrid, 256, 0, stream>>>(bufA, hWa, rs, ssrc, Wt2, brel2, hWb, bufB);
  // layer 3: A = relu(bufB + gather(hWb)); hWa = A@Wrel3, bufA = A@Wroot3 + b3
  gemm_agg_mfma<<<ggrid, 256, 0, stream>>>(bufB, hWb, rs, ssrc, Wt3, brel3, hWa, bufA);
  // pool: h3 = relu(bufA + gather(hWa)), mean per graph, MLP head
  pool_head_kernel<<<GRAPHS, 256, 0, stream>>>(bufA, hWa, rs, ssrc, gstart,
                                               Wfc1, bfc1, Wfc2, bfc2, (float*)d_out);
}

// Round 7
// 160.593 us; speedup vs baseline: 1.7869x; 1.7869x over previous
//
#include <hip/hip_runtime.h>
#include <cstdint>
#include <cstddef>

#define NN 50000
#define NE 800000
#define GRAPHS 512
#define NBK 782                               // ceil(50000/64) buckets of 64 nodes

typedef __attribute__((ext_vector_type(8))) short bf16x8;
typedef __attribute__((ext_vector_type(4))) float f32x4;

__device__ __forceinline__ unsigned short f2bf(float f) {
  union { float f; unsigned u; } v; v.f = f;
  unsigned r = v.u + 0x7FFF + ((v.u >> 16) & 1);   // RNE
  return (unsigned short)(r >> 16);
}
__device__ __forceinline__ float bf2f(unsigned short h) {
  union { unsigned u; float f; } v; v.u = ((unsigned)h) << 16;
  return v.f;
}
// relu on two packed bf16 (zero the 16-bit lane if its sign bit is set)
__device__ __forceinline__ unsigned relu2(unsigned v) {
  unsigned m = (v & 0x80008000u) >> 15;
  return v & ~(m * 0xFFFFu);
}

// ---------- setup: zero bcnt + graph bounds + weight transpose/cast ----------
__global__ __launch_bounds__(256) void setup_kernel(
    const int* __restrict__ batch, int* __restrict__ gstart,
    int* __restrict__ bcnt,
    const float* __restrict__ Wrel1, const float* __restrict__ Wroot1,
    const float* __restrict__ Wrel2, const float* __restrict__ Wroot2,
    const float* __restrict__ Wrel3, const float* __restrict__ Wroot3,
    unsigned short* __restrict__ Wt1, unsigned short* __restrict__ Wt2,
    unsigned short* __restrict__ Wt3) {
  const int tid = blockIdx.x * 256 + threadIdx.x;
  const int stride = gridDim.x * 256;
  for (int i = tid; i < NBK; i += stride) bcnt[i] = 0;
  for (int g = tid; g <= GRAPHS; g += stride) {
    int lo = 0, hi = NN;                      // lower_bound(batch, g)
    while (lo < hi) {
      int mid = (lo + hi) >> 1;
      if (batch[mid] < g) lo = mid + 1; else hi = mid;
    }
    gstart[g] = lo;
  }
  for (int idx = tid; idx < 128 * 128; idx += stride) {
    int c = idx >> 7, k = idx & 127;
    Wt1[c * 128 + k] = f2bf(c < 64 ? Wrel1[k * 64 + c] : Wroot1[k * 64 + (c - 64)]);
  }
  for (int idx = tid; idx < 128 * 64; idx += stride) {
    int c = idx >> 6, k = idx & 63;
    Wt2[c * 64 + k] = f2bf(c < 64 ? Wrel2[k * 64 + c] : Wroot2[k * 64 + (c - 64)]);
    Wt3[c * 64 + k] = f2bf(c < 64 ? Wrel3[k * 64 + c] : Wroot3[k * 64 + (c - 64)]);
  }
}

// ============ hierarchical CSR build (bucket = 64 consecutive nodes) ============

__global__ __launch_bounds__(256) void bcount_kernel(const int* __restrict__ dst,
                                                     int* __restrict__ bcnt) {
  __shared__ int hist[NBK];
  const int t = threadIdx.x;
  for (int b = t; b < NBK; b += 256) hist[b] = 0;
  __syncthreads();
  const int e0 = blockIdx.x * 2048;
  #pragma unroll
  for (int i = 0; i < 8; ++i) {
    int e = e0 + i * 256 + t;
    if (e < NE) atomicAdd(&hist[dst[e] >> 6], 1);
  }
  __syncthreads();
  for (int b = t; b < NBK; b += 256) {
    int c = hist[b];
    if (c) atomicAdd(&bcnt[b], c);
  }
}

__global__ __launch_bounds__(1024) void bscan_kernel(const int* __restrict__ bcnt,
                                                     int* __restrict__ bbase,
                                                     int* __restrict__ bcur) {
  __shared__ int sd[1024];
  const int t = threadIdx.x;
  int v = (t < NBK) ? bcnt[t] : 0;
  sd[t] = v;
  __syncthreads();
  for (int off = 1; off < 1024; off <<= 1) {
    int u = (t >= off) ? sd[t - off] : 0;
    __syncthreads();
    sd[t] += u;
    __syncthreads();
  }
  if (t < NBK) { int ex = sd[t] - v; bbase[t] = ex; bcur[t] = ex; }
  if (t == NBK - 1) bbase[NBK] = sd[t];      // = NE
}

// packed edge: (dst&63)<<17 | src   (src < 2^17)
__global__ __launch_bounds__(256) void bin_kernel(const int* __restrict__ src,
                                                  const int* __restrict__ dst,
                                                  int* __restrict__ bcur,
                                                  unsigned* __restrict__ ebuf) {
  __shared__ int hist[NBK];
  __shared__ int base[NBK];
  __shared__ int lcur[NBK];
  const int t = threadIdx.x;
  for (int b = t; b < NBK; b += 256) { hist[b] = 0; lcur[b] = 0; }
  __syncthreads();
  const int e0 = blockIdx.x * 4096;
  unsigned pk[16]; int bk[16];
  #pragma unroll
  for (int i = 0; i < 16; ++i) {
    int e = e0 + i * 256 + t;
    if (e < NE) {
      int s = src[e], d = dst[e];
      bk[i] = d >> 6;
      pk[i] = ((unsigned)(d & 63) << 17) | (unsigned)s;
      atomicAdd(&hist[bk[i]], 1);
    } else bk[i] = -1;
  }
  __syncthreads();
  for (int b = t; b < NBK; b += 256) {
    int c = hist[b];
    if (c) base[b] = atomicAdd(&bcur[b], c);
  }
  __syncthreads();
  #pragma unroll
  for (int i = 0; i < 16; ++i) {
    if (bk[i] >= 0) {
      int r = atomicAdd(&lcur[bk[i]], 1);
      ebuf[base[bk[i]] + r] = pk[i];
    }
  }
}

__global__ __launch_bounds__(256) void bucket_csr_kernel(const unsigned* __restrict__ ebuf,
                                                         const int* __restrict__ bbase,
                                                         int* __restrict__ row_start,
                                                         int* __restrict__ ssrc) {
  __shared__ int ehist[64];
  __shared__ int sd[64];
  __shared__ int ecur[64];
  const int t = threadIdx.x;
  const int b = blockIdx.x;
  const int n0 = b << 6;
  const int e0 = bbase[b], e1 = bbase[b + 1];
  if (t < 64) ehist[t] = 0;
  __syncthreads();
  for (int e = e0 + t; e < e1; e += 256)
    atomicAdd(&ehist[ebuf[e] >> 17], 1);
  __syncthreads();
  if (t < 64) sd[t] = ehist[t];
  __syncthreads();
  for (int off = 1; off < 64; off <<= 1) {
    int u = (t >= off && t < 64) ? sd[t - off] : 0;
    __syncthreads();
    if (t < 64) sd[t] += u;
    __syncthreads();
  }
  if (t < 64) {
    int ex = e0 + sd[t] - ehist[t];
    ecur[t] = ex;
    if (n0 + t <= NN) row_start[n0 + t] = ex;
  }
  __syncthreads();
  for (int e = e0 + t; e < e1; e += 256) {
    unsigned ed = ebuf[e];
    int r = atomicAdd(&ecur[ed >> 17], 1);
    ssrc[r] = (int)(ed & 0x1FFFF);
  }
}

// ----------------- layer-1 MFMA GEMM: [hW | buf] = x @ [Wrel | Wroot] ------------
__global__ __launch_bounds__(256) void gemm_mfma_l1(const float* __restrict__ h,
    const unsigned short* __restrict__ Wt,    // [128][128] bf16 (pre-transposed)
    const float* __restrict__ brel,
    unsigned short* __restrict__ hW,          // [NN][64] bf16 (rel result)
    unsigned short* __restrict__ buf) {       // [NN][64] bf16 (root + bias)
  constexpr int K = 128;
  __shared__ __align__(16) unsigned short as[64 * K];
  __shared__ __align__(16) unsigned short bs[128 * K];
  constexpr int SEG = K / 8;
  const int t = threadIdx.x;
  const int row0 = blockIdx.x * 64;

  for (int idx = t; idx < 64 * SEG; idx += 256) {
    int r = idx / SEG, kq = idx % SEG;
    int node = row0 + r;
    float4 v0 = make_float4(0.f, 0.f, 0.f, 0.f), v1 = v0;
    if (node < NN) {
      const float* p = &h[(size_t)node * K + kq * 8];
      v0 = *(const float4*)p; v1 = *(const float4*)(p + 4);
    }
    uint4 p;
    p.x = f2bf(v0.x) | ((unsigned)f2bf(v0.y) << 16);
    p.y = f2bf(v0.z) | ((unsigned)f2bf(v0.w) << 16);
    p.z = f2bf(v1.x) | ((unsigned)f2bf(v1.y) << 16);
    p.w = f2bf(v1.z) | ((unsigned)f2bf(v1.w) << 16);
    int sidx = (r * K + kq * 8) ^ ((r & 7) << 3);
    *(uint4*)&as[sidx] = p;
  }
  for (int idx = t; idx < 128 * SEG; idx += 256) {
    int c = idx / SEG, kq = idx % SEG;
    uint4 v = *(const uint4*)&Wt[c * K + kq * 8];
    int sidx = (c * K + kq * 8) ^ ((c & 7) << 3);
    *(uint4*)&bs[sidx] = v;
  }
  __syncthreads();

  const int lane = t & 63, wave = t >> 6;
  const int li = lane & 15;
  const int kg = (lane >> 4) * 8;
  const int ar = wave * 16 + li;
  f32x4 acc[8];
  #pragma unroll
  for (int i = 0; i < 8; ++i) acc[i] = (f32x4){0.f, 0.f, 0.f, 0.f};

  #pragma unroll
  for (int k0 = 0; k0 < K; k0 += 32) {
    int ka = k0 + kg;
    bf16x8 a = *(bf16x8*)&as[(ar * K + ka) ^ ((ar & 7) << 3)];
    #pragma unroll
    for (int nb = 0; nb < 8; ++nb) {
      int bc = nb * 16 + li;
      bf16x8 b = *(bf16x8*)&bs[(bc * K + ka) ^ ((bc & 7) << 3)];
      acc[nb] = __builtin_amdgcn_mfma_f32_16x16x32_bf16(a, b, acc[nb], 0, 0, 0);
    }
  }

  const int orow = row0 + wave * 16 + (lane >> 4) * 4;
  #pragma unroll
  for (int nb = 0; nb < 4; ++nb) {            // rel half -> hW
    #pragma unroll
    for (int r = 0; r < 4; ++r) {
      int node = orow + r;
      if (node < NN) hW[(size_t)node * 64 + nb * 16 + li] = f2bf(acc[nb][r]);
    }
  }
  #pragma unroll
  for (int nb = 4; nb < 8; ++nb) {            // root half -> buf (bf16, + bias)
    float bb = brel[(nb - 4) * 16 + li];
    #pragma unroll
    for (int r = 0; r < 4; ++r) {
      int node = orow + r;
      if (node < NN) buf[(size_t)node * 64 + (nb - 4) * 16 + li] = f2bf(acc[nb][r] + bb);
    }
  }
}

// -------- layers 2/3 GEMM: A = relu(bufin) [bf16], [hW | buf] = A @ [Wrel|Wroot] ----
__global__ __launch_bounds__(256) void gemm_mfma_l23(
    const unsigned short* __restrict__ bufin, // [NN][64] bf16 (root + agg, pre-relu)
    const unsigned short* __restrict__ Wt,    // [128][64] bf16
    const float* __restrict__ brel,
    unsigned short* __restrict__ hW,
    unsigned short* __restrict__ buf) {
  constexpr int K = 64;
  __shared__ __align__(16) unsigned short as[64 * K];
  __shared__ __align__(16) unsigned short bs[128 * K];
  const int t = threadIdx.x;
  const int row0 = blockIdx.x * 64;

  for (int idx = t; idx < 64 * 8; idx += 256) {   // A: 64 rows x 8 chunks of 8 bf16
    int r = idx >> 3, kq = idx & 7;
    int node = row0 + r;
    uint4 v = make_uint4(0, 0, 0, 0);
    if (node < NN) v = *(const uint4*)&bufin[(size_t)node * 64 + kq * 8];
    v.x = relu2(v.x); v.y = relu2(v.y); v.z = relu2(v.z); v.w = relu2(v.w);
    int sidx = (r * K + kq * 8) ^ ((r & 7) << 3);
    *(uint4*)&as[sidx] = v;
  }
  for (int idx = t; idx < 128 * 8; idx += 256) {  // B: 128 cols x 8 chunks
    int c = idx >> 3, kq = idx & 7;
    uint4 v = *(const uint4*)&Wt[c * K + kq * 8];
    int sidx = (c * K + kq * 8) ^ ((c & 7) << 3);
    *(uint4*)&bs[sidx] = v;
  }
  __syncthreads();

  const int lane = t & 63, wave = t >> 6;
  const int li = lane & 15;
  const int kg = (lane >> 4) * 8;
  const int ar = wave * 16 + li;
  f32x4 acc[8];
  #pragma unroll
  for (int i = 0; i < 8; ++i) acc[i] = (f32x4){0.f, 0.f, 0.f, 0.f};

  #pragma unroll
  for (int k0 = 0; k0 < K; k0 += 32) {
    int ka = k0 + kg;
    bf16x8 a = *(bf16x8*)&as[(ar * K + ka) ^ ((ar & 7) << 3)];
    #pragma unroll
    for (int nb = 0; nb < 8; ++nb) {
      int bc = nb * 16 + li;
      bf16x8 b = *(bf16x8*)&bs[(bc * K + ka) ^ ((bc & 7) << 3)];
      acc[nb] = __builtin_amdgcn_mfma_f32_16x16x32_bf16(a, b, acc[nb], 0, 0, 0);
    }
  }

  const int orow = row0 + wave * 16 + (lane >> 4) * 4;
  #pragma unroll
  for (int nb = 0; nb < 4; ++nb) {
    #pragma unroll
    for (int r = 0; r < 4; ++r) {
      int node = orow + r;
      if (node < NN) hW[(size_t)node * 64 + nb * 16 + li] = f2bf(acc[nb][r]);
    }
  }
  #pragma unroll
  for (int nb = 4; nb < 8; ++nb) {
    float bb = brel[(nb - 4) * 16 + li];
    #pragma unroll
    for (int r = 0; r < 4; ++r) {
      int node = orow + r;
      if (node < NN) buf[(size_t)node * 64 + (nb - 4) * 16 + li] = f2bf(acc[nb][r] + bb);
    }
  }
}

// ------ CSR aggregation: buf[n] += sum hW[src]  (bf16 in/out, f32 accumulate) ------
__global__ __launch_bounds__(256) void aggregate_kernel(
    const unsigned short* __restrict__ hW,
    const int* __restrict__ rs, const int* __restrict__ ssrc,
    unsigned short* __restrict__ buf) {
  int tid = blockIdx.x * 256 + threadIdx.x;
  int node = tid >> 4, c4 = (tid & 15) * 4;
  if (node >= NN) return;
  const int s0 = rs[node], s1 = rs[node + 1];
  ushort4 b = *(const ushort4*)&buf[(size_t)node * 64 + c4];
  float4 a0 = make_float4(bf2f(b.x), bf2f(b.y), bf2f(b.z), bf2f(b.w));
  float4 a1 = make_float4(0.f, 0.f, 0.f, 0.f);
  int e = s0;
  for (; e + 2 <= s1; e += 2) {               // 2-way unroll, independent chains
    int sA = ssrc[e], sB = ssrc[e + 1];
    ushort4 uA = *(const ushort4*)&hW[(size_t)sA * 64 + c4];
    ushort4 uB = *(const ushort4*)&hW[(size_t)sB * 64 + c4];
    a0.x += bf2f(uA.x); a0.y += bf2f(uA.y); a0.z += bf2f(uA.z); a0.w += bf2f(uA.w);
    a1.x += bf2f(uB.x); a1.y += bf2f(uB.y); a1.z += bf2f(uB.z); a1.w += bf2f(uB.w);
  }
  if (e < s1) {
    int sA = ssrc[e];
    ushort4 uA = *(const ushort4*)&hW[(size_t)sA * 64 + c4];
    a0.x += bf2f(uA.x); a0.y += bf2f(uA.y); a0.z += bf2f(uA.z); a0.w += bf2f(uA.w);
  }
  a0.x += a1.x; a0.y += a1.y; a0.z += a1.z; a0.w += a1.w;
  ushort4 o;
  o.x = f2bf(a0.x); o.y = f2bf(a0.y); o.z = f2bf(a0.z); o.w = f2bf(a0.w);
  *(ushort4*)&buf[(size_t)node * 64 + c4] = o;
}

// ------- mean-pool (relu on load) + MLP head: one block per graph -------
__global__ __launch_bounds__(256) void pool_head_kernel(
    const unsigned short* __restrict__ buf,   // [NN][64] bf16 (pre-relu h3)
    const int* __restrict__ gstart,
    const float* __restrict__ Wfc1, const float* __restrict__ bfc1,
    const float* __restrict__ Wfc2, const float* __restrict__ bfc2,
    float* __restrict__ out) {
  __shared__ float ps[16][64];
  __shared__ float m[64];
  __shared__ float h1[32];
  const int g = blockIdx.x, t = threadIdx.x;
  const int grp = t >> 4, l16 = t & 15;
  const int s0 = gstart[g], s1 = gstart[g + 1];
  float4 acc = make_float4(0.f, 0.f, 0.f, 0.f);
  for (int i = s0 + grp; i < s1; i += 16) {
    ushort4 u = *(const ushort4*)&buf[(size_t)i * 64 + l16 * 4];
    acc.x += fmaxf(bf2f(u.x), 0.f); acc.y += fmaxf(bf2f(u.y), 0.f);
    acc.z += fmaxf(bf2f(u.z), 0.f); acc.w += fmaxf(bf2f(u.w), 0.f);
  }
  *(float4*)&ps[grp][l16 * 4] = acc;
  __syncthreads();
  if (t < 64) {
    float s = 0.f;
    #pragma unroll
    for (int p = 0; p < 16; ++p) s += ps[p][t];
    m[t] = s / fmaxf((float)(s1 - s0), 1.0f);
  }
  __syncthreads();
  if (t < 32) {
    float a = bfc1[t];
    #pragma unroll
    for (int k = 0; k < 64; ++k) a += m[k] * Wfc1[k * 32 + t];
    h1[t] = fmaxf(a, 0.f);
  }
  __syncthreads();
  if (t == 0) {
    float o = bfc2[0];
    #pragma unroll
    for (int j = 0; j < 32; ++j) o += h1[j] * Wfc2[j];
    out[g] = o;
  }
}

extern "C" void kernel_launch(void* const* d_in, const int* in_sizes, int n_in,
                              void* d_out, int out_size, void* d_ws, size_t ws_size,
                              hipStream_t stream) {
  const float* x      = (const float*)d_in[0];
  const int*   ei     = (const int*)d_in[1];
  const int*   batch  = (const int*)d_in[2];
  const float* Wrel1  = (const float*)d_in[3];
  const float* brel1  = (const float*)d_in[4];
  const float* Wroot1 = (const float*)d_in[5];
  const float* Wrel2  = (const float*)d_in[6];
  const float* brel2  = (const float*)d_in[7];
  const float* Wroot2 = (const float*)d_in[8];
  const float* Wrel3  = (const float*)d_in[9];
  const float* brel3  = (const float*)d_in[10];
  const float* Wroot3 = (const float*)d_in[11];
  const float* Wfc1   = (const float*)d_in[12];
  const float* bfc1   = (const float*)d_in[13];
  const float* Wfc2   = (const float*)d_in[14];
  const float* bfc2   = (const float*)d_in[15];
  const int* src = ei;
  const int* dst = ei + NE;

  char* w = (char*)d_ws;
  auto alloc = [&](size_t bytes) -> char* {
    char* p = w; w += (bytes + 255) & ~(size_t)255; return p;
  };
  unsigned short* hW   = (unsigned short*)alloc((size_t)NN * 64 * 2);  // bf16
  unsigned short* bufA = (unsigned short*)alloc((size_t)NN * 64 * 2);  // bf16
  unsigned short* bufB = (unsigned short*)alloc((size_t)NN * 64 * 2);  // bf16
  int*   rs     = (int*)alloc((size_t)(NN + 1) * 4);
  int*   ssrc   = (int*)alloc((size_t)NE * 4);
  int*   gstart = (int*)alloc((size_t)(GRAPHS + 1) * 4);
  int*   bcnt   = (int*)alloc((size_t)NBK * 4);
  int*   bbase  = (int*)alloc((size_t)(NBK + 1) * 4);
  int*   bcur   = (int*)alloc((size_t)NBK * 4);
  unsigned short* Wt1 = (unsigned short*)alloc((size_t)128 * 128 * 2);
  unsigned short* Wt2 = (unsigned short*)alloc((size_t)128 * 64 * 2);
  unsigned short* Wt3 = (unsigned short*)alloc((size_t)128 * 64 * 2);
  // ebuf (3.2MB) aliases bufA+bufB region? bufB (6.4MB bf16) alone covers it;
  // bufB is first written by gemm_l23 layer-2, after bucket_csr has consumed ebuf.
  unsigned* ebuf = (unsigned*)bufB;

  setup_kernel<<<64, 256, 0, stream>>>(batch, gstart, bcnt,
                                       Wrel1, Wroot1, Wrel2, Wroot2, Wrel3, Wroot3,
                                       Wt1, Wt2, Wt3);
  bcount_kernel<<<(NE + 2047) / 2048, 256, 0, stream>>>(dst, bcnt);
  bscan_kernel<<<1, 1024, 0, stream>>>(bcnt, bbase, bcur);
  bin_kernel<<<(NE + 4095) / 4096, 256, 0, stream>>>(src, dst, bcur, ebuf);
  bucket_csr_kernel<<<NBK, 256, 0, stream>>>(ebuf, bbase, rs, ssrc);

  const int ggrid = (NN + 63) / 64;          // 782
  const int agrid = (NN * 16 + 255) / 256;   // 3125

  // layer 1: hW = x@Wrel1, bufA = x@Wroot1 + b1
  gemm_mfma_l1<<<ggrid, 256, 0, stream>>>(x, Wt1, brel1, hW, bufA);
  aggregate_kernel<<<agrid, 256, 0, stream>>>(hW, rs, ssrc, bufA);
  // layer 2: A = relu(bufA); hW = A@Wrel2, bufB = A@Wroot2 + b2
  gemm_mfma_l23<<<ggrid, 256, 0, stream>>>(bufA, Wt2, brel2, hW, bufB);
  aggregate_kernel<<<agrid, 256, 0, stream>>>(hW, rs, ssrc, bufB);
  // layer 3
  gemm_mfma_l23<<<ggrid, 256, 0, stream>>>(bufB, Wt3, brel3, hW, bufA);
  aggregate_kernel<<<agrid, 256, 0, stream>>>(hW, rs, ssrc, bufA);

  pool_head_kernel<<<GRAPHS, 256, 0, stream>>>(bufA, gstart, Wfc1, bfc1, Wfc2, bfc2,
                                               (float*)d_out);
}

// Round 8
// 132.462 us; speedup vs baseline: 2.1664x; 1.2124x over previous
//
#include <hip/hip_runtime.h>
#include <cstdint>
#include <cstddef>

#define NN 50000
#define NE 800000
#define GRAPHS 512
#define NBK 782                               // ceil(50000/64) buckets of 64 nodes
#define CAP 2048                              // edge capacity per bucket (mean 1024)

typedef __attribute__((ext_vector_type(8))) short bf16x8;
typedef __attribute__((ext_vector_type(4))) float f32x4;
typedef __attribute__((ext_vector_type(2))) float f32x2;

__device__ __forceinline__ unsigned short f2bf(float f) {
  union { float f; unsigned u; } v; v.f = f;
  unsigned r = v.u + 0x7FFF + ((v.u >> 16) & 1);   // RNE
  return (unsigned short)(r >> 16);
}
__device__ __forceinline__ float bf2f(unsigned short h) {
  union { unsigned u; float f; } v; v.u = ((unsigned)h) << 16;
  return v.f;
}
// relu on two packed bf16 (zero the 16-bit lane if its sign bit is set)
__device__ __forceinline__ unsigned relu2(unsigned v) {
  unsigned m = (v & 0x80008000u) >> 15;
  return v & ~(m * 0xFFFFu);
}

// ---------------- fp8 e4m3fn helpers (HW cvt with SW fallback) ----------------
__device__ __forceinline__ unsigned char f2fp8_sw(float f) {
  union { float f; unsigned u; } v; v.f = f;
  unsigned s = (v.u >> 24) & 0x80;
  unsigned u = v.u & 0x7fffffffu;
  if (u < 0x3c000000u) {                      // |f| < 2^-7: subnormal/flush
    float a = fabsf(f) * 512.0f;
    int mi = (int)(a + 0.5f); if (mi > 7) mi = 7;
    return (unsigned char)(s | mi);
  }
  unsigned r = u + 0x7FFFF + ((u >> 20) & 1); // RNE to 3 mantissa bits
  int e = (int)(r >> 23) - 127;
  unsigned m = (r >> 20) & 7;
  if (e > 8) { e = 8; m = 6; }                // clamp to 448
  return (unsigned char)(s | ((unsigned)(e + 7) << 3) | m);
}
__device__ __forceinline__ float fp82f_sw(unsigned b) {
  unsigned s = (b & 0x80) << 24;
  unsigned e = (b >> 3) & 0xF, m = b & 7;
  union { unsigned u; float f; } v;
  if (e == 0) {
    float sub = (float)m * 0.001953125f;      // m * 2^-9
    return (b & 0x80) ? -sub : sub;
  }
  v.u = s | ((e + 120) << 23) | (m << 20);
  return v.f;
}
__device__ __forceinline__ void fp8pair(float a, float b,
                                        unsigned char& c0, unsigned char& c1) {
#if __has_builtin(__builtin_amdgcn_cvt_pk_fp8_f32)
  int p = __builtin_amdgcn_cvt_pk_fp8_f32(a, b, 0, false);
  c0 = (unsigned char)(p & 0xFF); c1 = (unsigned char)((p >> 8) & 0xFF);
#else
  c0 = f2fp8_sw(a); c1 = f2fp8_sw(b);
#endif
}
__device__ __forceinline__ float4 fp8x4_dec(unsigned u) {
#if __has_builtin(__builtin_amdgcn_cvt_pk_f32_fp8)
  f32x2 lo = __builtin_amdgcn_cvt_pk_f32_fp8((int)u, false);
  f32x2 hi = __builtin_amdgcn_cvt_pk_f32_fp8((int)u, true);
  return make_float4(lo[0], lo[1], hi[0], hi[1]);
#else
  return make_float4(fp82f_sw(u & 0xFF), fp82f_sw((u >> 8) & 0xFF),
                     fp82f_sw((u >> 16) & 0xFF), fp82f_sw((u >> 24) & 0xFF));
#endif
}

// ---------- setup: zero bcnt + graph bounds + weight transpose/cast ----------
__global__ __launch_bounds__(256) void setup_kernel(
    const int* __restrict__ batch, int* __restrict__ gstart,
    int* __restrict__ bcnt,
    const float* __restrict__ Wrel1, const float* __restrict__ Wroot1,
    const float* __restrict__ Wrel2, const float* __restrict__ Wroot2,
    const float* __restrict__ Wrel3, const float* __restrict__ Wroot3,
    unsigned short* __restrict__ Wt1, unsigned short* __restrict__ Wt2,
    unsigned short* __restrict__ Wt3) {
  const int tid = blockIdx.x * 256 + threadIdx.x;
  const int stride = gridDim.x * 256;
  for (int i = tid; i < NBK; i += stride) bcnt[i] = 0;
  for (int g = tid; g <= GRAPHS; g += stride) {
    int lo = 0, hi = NN;                      // lower_bound(batch, g)
    while (lo < hi) {
      int mid = (lo + hi) >> 1;
      if (batch[mid] < g) lo = mid + 1; else hi = mid;
    }
    gstart[g] = lo;
  }
  for (int idx = tid; idx < 128 * 128; idx += stride) {
    int c = idx >> 7, k = idx & 127;
    Wt1[c * 128 + k] = f2bf(c < 64 ? Wrel1[k * 64 + c] : Wroot1[k * 64 + (c - 64)]);
  }
  for (int idx = tid; idx < 128 * 64; idx += stride) {
    int c = idx >> 6, k = idx & 63;
    Wt2[c * 64 + k] = f2bf(c < 64 ? Wrel2[k * 64 + c] : Wroot2[k * 64 + (c - 64)]);
    Wt3[c * 64 + k] = f2bf(c < 64 ? Wrel3[k * 64 + c] : Wroot3[k * 64 + (c - 64)]);
  }
}

// ====== CSR build: direct-reservation binning into fixed-capacity buckets ======
// packed edge: (dst&63)<<17 | src   (src < 2^17)
__global__ __launch_bounds__(256) void bin_kernel(const int* __restrict__ src,
                                                  const int* __restrict__ dst,
                                                  int* __restrict__ bcnt,
                                                  unsigned* __restrict__ ebuf) {
  __shared__ int hist[NBK];
  __shared__ int base[NBK];
  __shared__ int lcur[NBK];
  const int t = threadIdx.x;
  for (int b = t; b < NBK; b += 256) { hist[b] = 0; lcur[b] = 0; }
  __syncthreads();
  const int e0 = blockIdx.x * 4096;
  unsigned pk[16]; int bk[16];
  #pragma unroll
  for (int i = 0; i < 16; ++i) {
    int e = e0 + i * 256 + t;
    if (e < NE) {
      int s = src[e], d = dst[e];
      bk[i] = d >> 6;
      pk[i] = ((unsigned)(d & 63) << 17) | (unsigned)s;
      atomicAdd(&hist[bk[i]], 1);
    } else bk[i] = -1;
  }
  __syncthreads();
  for (int b = t; b < NBK; b += 256) {
    int c = hist[b];
    if (c) base[b] = atomicAdd(&bcnt[b], c);
  }
  __syncthreads();
  #pragma unroll
  for (int i = 0; i < 16; ++i) {
    if (bk[i] >= 0) {
      int r = atomicAdd(&lcur[bk[i]], 1);
      ebuf[(size_t)bk[i] * CAP + base[bk[i]] + r] = pk[i];
    }
  }
}

// per-bucket counting sort in LDS -> per-node [rs, ren) ranges in bucketed ssrc
__global__ __launch_bounds__(256) void bucket_csr_kernel(const unsigned* __restrict__ ebuf,
                                                         const int* __restrict__ bcnt,
                                                         int* __restrict__ rs,
                                                         int* __restrict__ ren,
                                                         int* __restrict__ ssrc) {
  __shared__ int ehist[64];
  __shared__ int sd[64];
  __shared__ int ecur[64];
  const int t = threadIdx.x;
  const int b = blockIdx.x;
  const int n0 = b << 6;
  const int e0 = b * CAP;
  const int cnt = bcnt[b];
  if (t < 64) ehist[t] = 0;
  __syncthreads();
  for (int e = t; e < cnt; e += 256)
    atomicAdd(&ehist[ebuf[e0 + e] >> 17], 1);
  __syncthreads();
  if (t < 64) sd[t] = ehist[t];
  __syncthreads();
  for (int off = 1; off < 64; off <<= 1) {
    int u = (t >= off && t < 64) ? sd[t - off] : 0;
    __syncthreads();
    if (t < 64) sd[t] += u;
    __syncthreads();
  }
  if (t < 64) {
    int ex = e0 + sd[t] - ehist[t];
    ecur[t] = ex;
    rs[n0 + t] = ex;                          // arrays sized NBK*64 -> no guard
    ren[n0 + t] = e0 + sd[t];
  }
  __syncthreads();
  for (int e = t; e < cnt; e += 256) {
    unsigned ed = ebuf[e0 + e];
    int r = atomicAdd(&ecur[ed >> 17], 1);
    ssrc[r] = (int)(ed & 0x1FFFF);
  }
}

// ----------------- layer-1 MFMA GEMM: [hW | buf] = x @ [Wrel | Wroot] ------------
__global__ __launch_bounds__(256) void gemm_mfma_l1(const float* __restrict__ h,
    const unsigned short* __restrict__ Wt,    // [128][128] bf16 (pre-transposed)
    const float* __restrict__ brel,
    unsigned char* __restrict__ hW,           // [NN][64] fp8 (rel result)
    unsigned short* __restrict__ buf) {       // [NN][64] bf16 (root + bias)
  constexpr int K = 128;
  __shared__ __align__(16) unsigned short as[64 * K];
  __shared__ __align__(16) unsigned short bs[128 * K];
  constexpr int SEG = K / 8;
  const int t = threadIdx.x;
  const int row0 = blockIdx.x * 64;

  for (int idx = t; idx < 64 * SEG; idx += 256) {
    int r = idx / SEG, kq = idx % SEG;
    int node = row0 + r;
    float4 v0 = make_float4(0.f, 0.f, 0.f, 0.f), v1 = v0;
    if (node < NN) {
      const float* p = &h[(size_t)node * K + kq * 8];
      v0 = *(const float4*)p; v1 = *(const float4*)(p + 4);
    }
    uint4 p;
    p.x = f2bf(v0.x) | ((unsigned)f2bf(v0.y) << 16);
    p.y = f2bf(v0.z) | ((unsigned)f2bf(v0.w) << 16);
    p.z = f2bf(v1.x) | ((unsigned)f2bf(v1.y) << 16);
    p.w = f2bf(v1.z) | ((unsigned)f2bf(v1.w) << 16);
    int sidx = (r * K + kq * 8) ^ ((r & 7) << 3);
    *(uint4*)&as[sidx] = p;
  }
  for (int idx = t; idx < 128 * SEG; idx += 256) {
    int c = idx / SEG, kq = idx % SEG;
    uint4 v = *(const uint4*)&Wt[c * K + kq * 8];
    int sidx = (c * K + kq * 8) ^ ((c & 7) << 3);
    *(uint4*)&bs[sidx] = v;
  }
  __syncthreads();

  const int lane = t & 63, wave = t >> 6;
  const int li = lane & 15;
  const int kg = (lane >> 4) * 8;
  const int ar = wave * 16 + li;
  f32x4 acc[8];
  #pragma unroll
  for (int i = 0; i < 8; ++i) acc[i] = (f32x4){0.f, 0.f, 0.f, 0.f};

  #pragma unroll
  for (int k0 = 0; k0 < K; k0 += 32) {
    int ka = k0 + kg;
    bf16x8 a = *(bf16x8*)&as[(ar * K + ka) ^ ((ar & 7) << 3)];
    #pragma unroll
    for (int nb = 0; nb < 8; ++nb) {
      int bc = nb * 16 + li;
      bf16x8 b = *(bf16x8*)&bs[(bc * K + ka) ^ ((bc & 7) << 3)];
      acc[nb] = __builtin_amdgcn_mfma_f32_16x16x32_bf16(a, b, acc[nb], 0, 0, 0);
    }
  }

  const int orow = row0 + wave * 16 + (lane >> 4) * 4;
  #pragma unroll
  for (int nb = 0; nb < 4; ++nb) {            // rel half -> hW (fp8)
    unsigned char c0, c1, c2, c3;
    fp8pair(acc[nb][0], acc[nb][1], c0, c1);
    fp8pair(acc[nb][2], acc[nb][3], c2, c3);
    unsigned char cb[4] = {c0, c1, c2, c3};
    #pragma unroll
    for (int r = 0; r < 4; ++r) {
      int node = orow + r;
      if (node < NN) hW[(size_t)node * 64 + nb * 16 + li] = cb[r];
    }
  }
  #pragma unroll
  for (int nb = 4; nb < 8; ++nb) {            // root half -> buf (bf16, + bias)
    float bb = brel[(nb - 4) * 16 + li];
    #pragma unroll
    for (int r = 0; r < 4; ++r) {
      int node = orow + r;
      if (node < NN) buf[(size_t)node * 64 + (nb - 4) * 16 + li] = f2bf(acc[nb][r] + bb);
    }
  }
}

// -------- layers 2/3 GEMM: A = relu(bufin) [bf16], [hW | buf] = A @ [Wrel|Wroot] ----
__global__ __launch_bounds__(256) void gemm_mfma_l23(
    const unsigned short* __restrict__ bufin, // [NN][64] bf16 (root + agg, pre-relu)
    const unsigned short* __restrict__ Wt,    // [128][64] bf16
    const float* __restrict__ brel,
    unsigned char* __restrict__ hW,           // [NN][64] fp8
    unsigned short* __restrict__ buf) {
  constexpr int K = 64;
  __shared__ __align__(16) unsigned short as[64 * K];
  __shared__ __align__(16) unsigned short bs[128 * K];
  const int t = threadIdx.x;
  const int row0 = blockIdx.x * 64;

  for (int idx = t; idx < 64 * 8; idx += 256) {   // A: 64 rows x 8 chunks of 8 bf16
    int r = idx >> 3, kq = idx & 7;
    int node = row0 + r;
    uint4 v = make_uint4(0, 0, 0, 0);
    if (node < NN) v = *(const uint4*)&bufin[(size_t)node * 64 + kq * 8];
    v.x = relu2(v.x); v.y = relu2(v.y); v.z = relu2(v.z); v.w = relu2(v.w);
    int sidx = (r * K + kq * 8) ^ ((r & 7) << 3);
    *(uint4*)&as[sidx] = v;
  }
  for (int idx = t; idx < 128 * 8; idx += 256) {  // B: 128 cols x 8 chunks
    int c = idx >> 3, kq = idx & 7;
    uint4 v = *(const uint4*)&Wt[c * K + kq * 8];
    int sidx = (c * K + kq * 8) ^ ((c & 7) << 3);
    *(uint4*)&bs[sidx] = v;
  }
  __syncthreads();

  const int lane = t & 63, wave = t >> 6;
  const int li = lane & 15;
  const int kg = (lane >> 4) * 8;
  const int ar = wave * 16 + li;
  f32x4 acc[8];
  #pragma unroll
  for (int i = 0; i < 8; ++i) acc[i] = (f32x4){0.f, 0.f, 0.f, 0.f};

  #pragma unroll
  for (int k0 = 0; k0 < K; k0 += 32) {
    int ka = k0 + kg;
    bf16x8 a = *(bf16x8*)&as[(ar * K + ka) ^ ((ar & 7) << 3)];
    #pragma unroll
    for (int nb = 0; nb < 8; ++nb) {
      int bc = nb * 16 + li;
      bf16x8 b = *(bf16x8*)&bs[(bc * K + ka) ^ ((bc & 7) << 3)];
      acc[nb] = __builtin_amdgcn_mfma_f32_16x16x32_bf16(a, b, acc[nb], 0, 0, 0);
    }
  }

  const int orow = row0 + wave * 16 + (lane >> 4) * 4;
  #pragma unroll
  for (int nb = 0; nb < 4; ++nb) {
    unsigned char c0, c1, c2, c3;
    fp8pair(acc[nb][0], acc[nb][1], c0, c1);
    fp8pair(acc[nb][2], acc[nb][3], c2, c3);
    unsigned char cb[4] = {c0, c1, c2, c3};
    #pragma unroll
    for (int r = 0; r < 4; ++r) {
      int node = orow + r;
      if (node < NN) hW[(size_t)node * 64 + nb * 16 + li] = cb[r];
    }
  }
  #pragma unroll
  for (int nb = 4; nb < 8; ++nb) {
    float bb = brel[(nb - 4) * 16 + li];
    #pragma unroll
    for (int r = 0; r < 4; ++r) {
      int node = orow + r;
      if (node < NN) buf[(size_t)node * 64 + (nb - 4) * 16 + li] = f2bf(acc[nb][r] + bb);
    }
  }
}

// ------ CSR aggregation: buf[n] += sum hW[src]  (fp8 gather, f32 accumulate) ------
__global__ __launch_bounds__(256) void aggregate_kernel(
    const unsigned char* __restrict__ hW,     // [NN][64] fp8 (one 64B line per node)
    const int* __restrict__ rs, const int* __restrict__ ren,
    const int* __restrict__ ssrc,
    unsigned short* __restrict__ buf) {
  int tid = blockIdx.x * 256 + threadIdx.x;
  int node = tid >> 4, c4 = (tid & 15) * 4;
  if (node >= NN) return;
  const int s0 = rs[node], s1 = ren[node];
  ushort4 b = *(const ushort4*)&buf[(size_t)node * 64 + c4];
  float4 a0 = make_float4(bf2f(b.x), bf2f(b.y), bf2f(b.z), bf2f(b.w));
  float4 a1 = make_float4(0.f, 0.f, 0.f, 0.f);
  int e = s0;
  for (; e + 2 <= s1; e += 2) {               // 2-way unroll, independent chains
    int sA = ssrc[e], sB = ssrc[e + 1];
    unsigned uA = *(const unsigned*)&hW[(size_t)sA * 64 + c4];
    unsigned uB = *(const unsigned*)&hW[(size_t)sB * 64 + c4];
    float4 vA = fp8x4_dec(uA), vB = fp8x4_dec(uB);
    a0.x += vA.x; a0.y += vA.y; a0.z += vA.z; a0.w += vA.w;
    a1.x += vB.x; a1.y += vB.y; a1.z += vB.z; a1.w += vB.w;
  }
  if (e < s1) {
    unsigned uA = *(const unsigned*)&hW[(size_t)ssrc[e] * 64 + c4];
    float4 vA = fp8x4_dec(uA);
    a0.x += vA.x; a0.y += vA.y; a0.z += vA.z; a0.w += vA.w;
  }
  a0.x += a1.x; a0.y += a1.y; a0.z += a1.z; a0.w += a1.w;
  ushort4 o;
  o.x = f2bf(a0.x); o.y = f2bf(a0.y); o.z = f2bf(a0.z); o.w = f2bf(a0.w);
  *(ushort4*)&buf[(size_t)node * 64 + c4] = o;
}

// ------- mean-pool (relu on load) + MLP head: one block per graph -------
__global__ __launch_bounds__(256) void pool_head_kernel(
    const unsigned short* __restrict__ buf,   // [NN][64] bf16 (pre-relu h3)
    const int* __restrict__ gstart,
    const float* __restrict__ Wfc1, const float* __restrict__ bfc1,
    const float* __restrict__ Wfc2, const float* __restrict__ bfc2,
    float* __restrict__ out) {
  __shared__ float ps[16][64];
  __shared__ float m[64];
  __shared__ float h1[32];
  const int g = blockIdx.x, t = threadIdx.x;
  const int grp = t >> 4, l16 = t & 15;
  const int s0 = gstart[g], s1 = gstart[g + 1];
  float4 acc = make_float4(0.f, 0.f, 0.f, 0.f);
  for (int i = s0 + grp; i < s1; i += 16) {
    ushort4 u = *(const ushort4*)&buf[(size_t)i * 64 + l16 * 4];
    acc.x += fmaxf(bf2f(u.x), 0.f); acc.y += fmaxf(bf2f(u.y), 0.f);
    acc.z += fmaxf(bf2f(u.z), 0.f); acc.w += fmaxf(bf2f(u.w), 0.f);
  }
  *(float4*)&ps[grp][l16 * 4] = acc;
  __syncthreads();
  if (t < 64) {
    float s = 0.f;
    #pragma unroll
    for (int p = 0; p < 16; ++p) s += ps[p][t];
    m[t] = s / fmaxf((float)(s1 - s0), 1.0f);
  }
  __syncthreads();
  if (t < 32) {
    float a = bfc1[t];
    #pragma unroll
    for (int k = 0; k < 64; ++k) a += m[k] * Wfc1[k * 32 + t];
    h1[t] = fmaxf(a, 0.f);
  }
  __syncthreads();
  if (t == 0) {
    float o = bfc2[0];
    #pragma unroll
    for (int j = 0; j < 32; ++j) o += h1[j] * Wfc2[j];
    out[g] = o;
  }
}

extern "C" void kernel_launch(void* const* d_in, const int* in_sizes, int n_in,
                              void* d_out, int out_size, void* d_ws, size_t ws_size,
                              hipStream_t stream) {
  const float* x      = (const float*)d_in[0];
  const int*   ei     = (const int*)d_in[1];
  const int*   batch  = (const int*)d_in[2];
  const float* Wrel1  = (const float*)d_in[3];
  const float* brel1  = (const float*)d_in[4];
  const float* Wroot1 = (const float*)d_in[5];
  const float* Wrel2  = (const float*)d_in[6];
  const float* brel2  = (const float*)d_in[7];
  const float* Wroot2 = (const float*)d_in[8];
  const float* Wrel3  = (const float*)d_in[9];
  const float* brel3  = (const float*)d_in[10];
  const float* Wroot3 = (const float*)d_in[11];
  const float* Wfc1   = (const float*)d_in[12];
  const float* bfc1   = (const float*)d_in[13];
  const float* Wfc2   = (const float*)d_in[14];
  const float* bfc2   = (const float*)d_in[15];
  const int* src = ei;
  const int* dst = ei + NE;

  char* w = (char*)d_ws;
  auto alloc = [&](size_t bytes) -> char* {
    char* p = w; w += (bytes + 255) & ~(size_t)255; return p;
  };
  unsigned char*  hW   = (unsigned char*)alloc((size_t)NN * 64);       // fp8
  unsigned short* bufA = (unsigned short*)alloc((size_t)NN * 64 * 2);  // bf16
  unsigned short* bufB = (unsigned short*)alloc((size_t)NN * 64 * 2);  // bf16
  int*   rs     = (int*)alloc((size_t)NBK * 64 * 4);
  int*   ren    = (int*)alloc((size_t)NBK * 64 * 4);
  int*   ssrc   = (int*)alloc((size_t)NBK * CAP * 4);
  int*   gstart = (int*)alloc((size_t)(GRAPHS + 1) * 4);
  int*   bcnt   = (int*)alloc((size_t)NBK * 4);
  unsigned* ebuf = (unsigned*)alloc((size_t)NBK * CAP * 4);
  unsigned short* Wt1 = (unsigned short*)alloc((size_t)128 * 128 * 2);
  unsigned short* Wt2 = (unsigned short*)alloc((size_t)128 * 64 * 2);
  unsigned short* Wt3 = (unsigned short*)alloc((size_t)128 * 64 * 2);

  setup_kernel<<<64, 256, 0, stream>>>(batch, gstart, bcnt,
                                       Wrel1, Wroot1, Wrel2, Wroot2, Wrel3, Wroot3,
                                       Wt1, Wt2, Wt3);
  bin_kernel<<<(NE + 4095) / 4096, 256, 0, stream>>>(src, dst, bcnt, ebuf);
  bucket_csr_kernel<<<NBK, 256, 0, stream>>>(ebuf, bcnt, rs, ren, ssrc);

  const int ggrid = (NN + 63) / 64;          // 782
  const int agrid = (NN * 16 + 255) / 256;   // 3125

  // layer 1: hW = x@Wrel1 (fp8), bufA = x@Wroot1 + b1
  gemm_mfma_l1<<<ggrid, 256, 0, stream>>>(x, Wt1, brel1, hW, bufA);
  aggregate_kernel<<<agrid, 256, 0, stream>>>(hW, rs, ren, ssrc, bufA);
  // layer 2: A = relu(bufA); hW = A@Wrel2, bufB = A@Wroot2 + b2
  gemm_mfma_l23<<<ggrid, 256, 0, stream>>>(bufA, Wt2, brel2, hW, bufB);
  aggregate_kernel<<<agrid, 256, 0, stream>>>(hW, rs, ren, ssrc, bufB);
  // layer 3
  gemm_mfma_l23<<<ggrid, 256, 0, stream>>>(bufB, Wt3, brel3, hW, bufA);
  aggregate_kernel<<<agrid, 256, 0, stream>>>(hW, rs, ren, ssrc, bufA);

  pool_head_kernel<<<GRAPHS, 256, 0, stream>>>(bufA, gstart, Wfc1, bfc1, Wfc2, bfc2,
                                               (float*)d_out);
}

// Round 9
// 113.152 us; speedup vs baseline: 2.5361x; 1.1707x over previous
//
#include <hip/hip_runtime.h>
#include <cstdint>
#include <cstddef>

#define NN 50000
#define NE 800000
#define GRAPHS 512
#define NBK 782                               // ceil(50000/64) buckets of 64 nodes
#define CAP 2048                              // edge capacity per bucket (mean 1024)
#define GG1 782                               // gemm_l1 blocks in merged dispatch

typedef __attribute__((ext_vector_type(8))) short bf16x8;
typedef __attribute__((ext_vector_type(4))) float f32x4;
typedef __attribute__((ext_vector_type(2))) float f32x2;

__device__ __forceinline__ unsigned short f2bf(float f) {
  union { float f; unsigned u; } v; v.f = f;
  unsigned r = v.u + 0x7FFF + ((v.u >> 16) & 1);   // RNE
  return (unsigned short)(r >> 16);
}
__device__ __forceinline__ float bf2f(unsigned short h) {
  union { unsigned u; float f; } v; v.u = ((unsigned)h) << 16;
  return v.f;
}

// ---------------- fp8 e4m3fn helpers (HW cvt with SW fallback) ----------------
__device__ __forceinline__ unsigned char f2fp8_sw(float f) {
  union { float f; unsigned u; } v; v.f = f;
  unsigned s = (v.u >> 24) & 0x80;
  unsigned u = v.u & 0x7fffffffu;
  if (u < 0x3c000000u) {
    float a = fabsf(f) * 512.0f;
    int mi = (int)(a + 0.5f); if (mi > 7) mi = 7;
    return (unsigned char)(s | mi);
  }
  unsigned r = u + 0x7FFFF + ((u >> 20) & 1);
  int e = (int)(r >> 23) - 127;
  unsigned m = (r >> 20) & 7;
  if (e > 8) { e = 8; m = 6; }
  return (unsigned char)(s | ((unsigned)(e + 7) << 3) | m);
}
__device__ __forceinline__ float fp82f_sw(unsigned b) {
  unsigned s = (b & 0x80) << 24;
  unsigned e = (b >> 3) & 0xF, m = b & 7;
  union { unsigned u; float f; } v;
  if (e == 0) {
    float sub = (float)m * 0.001953125f;
    return (b & 0x80) ? -sub : sub;
  }
  v.u = s | ((e + 120) << 23) | (m << 20);
  return v.f;
}
__device__ __forceinline__ void fp8pair(float a, float b,
                                        unsigned char& c0, unsigned char& c1) {
#if __has_builtin(__builtin_amdgcn_cvt_pk_fp8_f32)
  int p = __builtin_amdgcn_cvt_pk_fp8_f32(a, b, 0, false);
  c0 = (unsigned char)(p & 0xFF); c1 = (unsigned char)((p >> 8) & 0xFF);
#else
  c0 = f2fp8_sw(a); c1 = f2fp8_sw(b);
#endif
}
__device__ __forceinline__ float4 fp8x4_dec(unsigned u) {
#if __has_builtin(__builtin_amdgcn_cvt_pk_f32_fp8)
  f32x2 lo = __builtin_amdgcn_cvt_pk_f32_fp8((int)u, false);
  f32x2 hi = __builtin_amdgcn_cvt_pk_f32_fp8((int)u, true);
  return make_float4(lo[0], lo[1], hi[0], hi[1]);
#else
  return make_float4(fp82f_sw(u & 0xFF), fp82f_sw((u >> 8) & 0xFF),
                     fp82f_sw((u >> 16) & 0xFF), fp82f_sw((u >> 24) & 0xFF));
#endif
}

// ---------- setup: zero bcnt + graph bounds + weight transpose/cast ----------
__global__ __launch_bounds__(256) void setup_kernel(
    const int* __restrict__ batch, int* __restrict__ gstart,
    int* __restrict__ bcnt,
    const float* __restrict__ Wrel1, const float* __restrict__ Wroot1,
    const float* __restrict__ Wrel2, const float* __restrict__ Wroot2,
    const float* __restrict__ Wrel3, const float* __restrict__ Wroot3,
    unsigned short* __restrict__ Wt1, unsigned short* __restrict__ Wt2,
    unsigned short* __restrict__ Wt3) {
  const int tid = blockIdx.x * 256 + threadIdx.x;
  const int stride = gridDim.x * 256;
  for (int i = tid; i < NBK; i += stride) bcnt[i] = 0;
  for (int g = tid; g <= GRAPHS; g += stride) {
    int lo = 0, hi = NN;                      // lower_bound(batch, g)
    while (lo < hi) {
      int mid = (lo + hi) >> 1;
      if (batch[mid] < g) lo = mid + 1; else hi = mid;
    }
    gstart[g] = lo;
  }
  for (int idx = tid; idx < 128 * 128; idx += stride) {
    int c = idx >> 7, k = idx & 127;
    Wt1[c * 128 + k] = f2bf(c < 64 ? Wrel1[k * 64 + c] : Wroot1[k * 64 + (c - 64)]);
  }
  for (int idx = tid; idx < 128 * 64; idx += stride) {
    int c = idx >> 6, k = idx & 63;
    Wt2[c * 64 + k] = f2bf(c < 64 ? Wrel2[k * 64 + c] : Wroot2[k * 64 + (c - 64)]);
    Wt3[c * 64 + k] = f2bf(c < 64 ? Wrel3[k * 64 + c] : Wroot3[k * 64 + (c - 64)]);
  }
}

// ======== merged dispatch: blocks [0,GG1) = layer-1 GEMM; rest = edge binning ======
// gemm: [hW | root] = x @ [Wrel1 | Wroot1], hW fp8, root bf16 (+bias)
// bin:  packed edge (dst&63)<<17 | src into fixed-capacity buckets
__global__ __launch_bounds__(256) void bin_gemm1_kernel(
    const float* __restrict__ h, const unsigned short* __restrict__ Wt,
    const float* __restrict__ brel,
    unsigned char* __restrict__ hW, unsigned short* __restrict__ root,
    const int* __restrict__ src, const int* __restrict__ dst,
    int* __restrict__ bcnt, unsigned* __restrict__ ebuf) {
  __shared__ __align__(16) char smem[49152];
  const int t = threadIdx.x;

  if (blockIdx.x < GG1) {                     // ---------- gemm_l1 ----------
    constexpr int K = 128;
    unsigned short* as = (unsigned short*)smem;            // 64*128*2 = 16KB
    unsigned short* bs = (unsigned short*)(smem + 16384);  // 128*128*2 = 32KB
    constexpr int SEG = K / 8;
    const int row0 = blockIdx.x * 64;

    for (int idx = t; idx < 64 * SEG; idx += 256) {
      int r = idx / SEG, kq = idx % SEG;
      int node = row0 + r;
      float4 v0 = make_float4(0.f, 0.f, 0.f, 0.f), v1 = v0;
      if (node < NN) {
        const float* p = &h[(size_t)node * K + kq * 8];
        v0 = *(const float4*)p; v1 = *(const float4*)(p + 4);
      }
      uint4 p;
      p.x = f2bf(v0.x) | ((unsigned)f2bf(v0.y) << 16);
      p.y = f2bf(v0.z) | ((unsigned)f2bf(v0.w) << 16);
      p.z = f2bf(v1.x) | ((unsigned)f2bf(v1.y) << 16);
      p.w = f2bf(v1.z) | ((unsigned)f2bf(v1.w) << 16);
      int sidx = (r * K + kq * 8) ^ ((r & 7) << 3);
      *(uint4*)&as[sidx] = p;
    }
    for (int idx = t; idx < 128 * SEG; idx += 256) {
      int c = idx / SEG, kq = idx % SEG;
      uint4 v = *(const uint4*)&Wt[c * K + kq * 8];
      int sidx = (c * K + kq * 8) ^ ((c & 7) << 3);
      *(uint4*)&bs[sidx] = v;
    }
    __syncthreads();

    const int lane = t & 63, wave = t >> 6;
    const int li = lane & 15;
    const int kg = (lane >> 4) * 8;
    const int ar = wave * 16 + li;
    f32x4 acc[8];
    #pragma unroll
    for (int i = 0; i < 8; ++i) acc[i] = (f32x4){0.f, 0.f, 0.f, 0.f};

    #pragma unroll
    for (int k0 = 0; k0 < K; k0 += 32) {
      int ka = k0 + kg;
      bf16x8 a = *(bf16x8*)&as[(ar * K + ka) ^ ((ar & 7) << 3)];
      #pragma unroll
      for (int nb = 0; nb < 8; ++nb) {
        int bc = nb * 16 + li;
        bf16x8 b = *(bf16x8*)&bs[(bc * K + ka) ^ ((bc & 7) << 3)];
        acc[nb] = __builtin_amdgcn_mfma_f32_16x16x32_bf16(a, b, acc[nb], 0, 0, 0);
      }
    }

    const int orow = row0 + wave * 16 + (lane >> 4) * 4;
    #pragma unroll
    for (int nb = 0; nb < 4; ++nb) {          // rel half -> hW (fp8)
      unsigned char cb[4];
      fp8pair(acc[nb][0], acc[nb][1], cb[0], cb[1]);
      fp8pair(acc[nb][2], acc[nb][3], cb[2], cb[3]);
      #pragma unroll
      for (int r = 0; r < 4; ++r) {
        int node = orow + r;
        if (node < NN) hW[(size_t)node * 64 + nb * 16 + li] = cb[r];
      }
    }
    #pragma unroll
    for (int nb = 4; nb < 8; ++nb) {          // root half -> bf16 (+bias)
      float bb = brel[(nb - 4) * 16 + li];
      #pragma unroll
      for (int r = 0; r < 4; ++r) {
        int node = orow + r;
        if (node < NN) root[(size_t)node * 64 + (nb - 4) * 16 + li] = f2bf(acc[nb][r] + bb);
      }
    }
  } else {                                    // ---------- bin ----------
    int* hist = (int*)smem;
    int* base = hist + NBK;
    int* lcur = base + NBK;
    for (int b = t; b < NBK; b += 256) { hist[b] = 0; lcur[b] = 0; }
    __syncthreads();
    const int e0 = (blockIdx.x - GG1) * 4096;
    unsigned pk[16]; int bk[16];
    #pragma unroll
    for (int i = 0; i < 16; ++i) {
      int e = e0 + i * 256 + t;
      if (e < NE) {
        int s = src[e], d = dst[e];
        bk[i] = d >> 6;
        pk[i] = ((unsigned)(d & 63) << 17) | (unsigned)s;
        atomicAdd(&hist[bk[i]], 1);
      } else bk[i] = -1;
    }
    __syncthreads();
    for (int b = t; b < NBK; b += 256) {
      int c = hist[b];
      if (c) base[b] = atomicAdd(&bcnt[b], c);
    }
    __syncthreads();
    #pragma unroll
    for (int i = 0; i < 16; ++i) {
      if (bk[i] >= 0) {
        int r = atomicAdd(&lcur[bk[i]], 1);
        ebuf[(size_t)bk[i] * CAP + base[bk[i]] + r] = pk[i];
      }
    }
  }
}

// per-bucket counting sort in LDS -> per-node [rs, ren) ranges in bucketed ssrc
__global__ __launch_bounds__(256) void bucket_csr_kernel(const unsigned* __restrict__ ebuf,
                                                         const int* __restrict__ bcnt,
                                                         int* __restrict__ rs,
                                                         int* __restrict__ ren,
                                                         int* __restrict__ ssrc) {
  __shared__ int ehist[64];
  __shared__ int sd[64];
  __shared__ int ecur[64];
  const int t = threadIdx.x;
  const int b = blockIdx.x;
  const int n0 = b << 6;
  const int e0 = b * CAP;
  const int cnt = bcnt[b];
  if (t < 64) ehist[t] = 0;
  __syncthreads();
  for (int e = t; e < cnt; e += 256)
    atomicAdd(&ehist[ebuf[e0 + e] >> 17], 1);
  __syncthreads();
  if (t < 64) sd[t] = ehist[t];
  __syncthreads();
  for (int off = 1; off < 64; off <<= 1) {
    int u = (t >= off && t < 64) ? sd[t - off] : 0;
    __syncthreads();
    if (t < 64) sd[t] += u;
    __syncthreads();
  }
  if (t < 64) {
    int ex = e0 + sd[t] - ehist[t];
    ecur[t] = ex;
    rs[n0 + t] = ex;
    ren[n0 + t] = e0 + sd[t];
  }
  __syncthreads();
  for (int e = t; e < cnt; e += 256) {
    unsigned ed = ebuf[e0 + e];
    int r = atomicAdd(&ecur[ed >> 17], 1);
    ssrc[r] = (int)(ed & 0x1FFFF);
  }
}

// ===== layers 2/3 fused: a = relu(root + G(hWp)); [hW | root'] = a @ [Wrel|Wroot] ====
// Block = 16 nodes; gather keeps aggregate's 16-lane/node geometry (full TLP).
__global__ __launch_bounds__(256) void agg_gemm_kernel(
    const unsigned short* __restrict__ rootPrev,  // [NN][64] bf16 (incl. prev bias)
    const unsigned char* __restrict__ hWp,        // [NN][64] fp8
    const int* __restrict__ rs, const int* __restrict__ ren,
    const int* __restrict__ ssrc,
    const unsigned short* __restrict__ Wt,        // [128][64] bf16
    const float* __restrict__ brel,               // this layer's b_rel
    unsigned char* __restrict__ hW,               // out fp8
    unsigned short* __restrict__ rootOut) {       // out bf16 (+bias)
  __shared__ __align__(16) unsigned short as[16 * 64];    // 2KB
  __shared__ __align__(16) unsigned short bs[128 * 64];   // 16KB
  const int t = threadIdx.x;
  const int n0 = blockIdx.x * 16;

  // stage B (swizzled) — issues early, overlaps gather latency
  #pragma unroll
  for (int i = 0; i < 4; ++i) {
    int idx = t + i * 256;
    int c = idx >> 3, kq = idx & 7;
    uint4 v = *(const uint4*)&Wt[c * 64 + kq * 8];
    int sidx = (c * 64 + kq * 8) ^ ((c & 7) << 3);
    *(uint4*)&bs[sidx] = v;
  }

  // gather: 16 lanes per node, fp8 rows, f32 accumulate; relu; bf16 into A-tile
  const int r = t >> 4, l16 = t & 15, c4 = l16 * 4;
  const int node = n0 + r;
  ushort4 rt = *(const ushort4*)&rootPrev[(size_t)node * 64 + c4];
  float4 a0 = make_float4(bf2f(rt.x), bf2f(rt.y), bf2f(rt.z), bf2f(rt.w));
  float4 a1 = make_float4(0.f, 0.f, 0.f, 0.f);
  const int s0 = rs[node], s1 = ren[node];
  int e = s0;
  for (; e + 2 <= s1; e += 2) {
    int sA = ssrc[e], sB = ssrc[e + 1];
    unsigned uA = *(const unsigned*)&hWp[(size_t)sA * 64 + c4];
    unsigned uB = *(const unsigned*)&hWp[(size_t)sB * 64 + c4];
    float4 vA = fp8x4_dec(uA), vB = fp8x4_dec(uB);
    a0.x += vA.x; a0.y += vA.y; a0.z += vA.z; a0.w += vA.w;
    a1.x += vB.x; a1.y += vB.y; a1.z += vB.z; a1.w += vB.w;
  }
  if (e < s1) {
    unsigned uA = *(const unsigned*)&hWp[(size_t)ssrc[e] * 64 + c4];
    float4 vA = fp8x4_dec(uA);
    a0.x += vA.x; a0.y += vA.y; a0.z += vA.z; a0.w += vA.w;
  }
  a0.x = fmaxf(a0.x + a1.x, 0.f); a0.y = fmaxf(a0.y + a1.y, 0.f);
  a0.z = fmaxf(a0.z + a1.z, 0.f); a0.w = fmaxf(a0.w + a1.w, 0.f);
  uint2 p;
  p.x = f2bf(a0.x) | ((unsigned)f2bf(a0.y) << 16);
  p.y = f2bf(a0.z) | ((unsigned)f2bf(a0.w) << 16);
  *(uint2*)&as[(r * 64 + c4) ^ ((r & 7) << 3)] = p;
  __syncthreads();

  // MFMA: wave w covers cols [w*32, w*32+32); rows = the block's 16 nodes
  const int lane = t & 63, wave = t >> 6;
  const int li = lane & 15, kg = (lane >> 4) * 8;
  f32x4 acc[2];
  acc[0] = (f32x4){0.f, 0.f, 0.f, 0.f};
  acc[1] = (f32x4){0.f, 0.f, 0.f, 0.f};
  #pragma unroll
  for (int ks = 0; ks < 2; ++ks) {
    int ka = ks * 32 + kg;
    bf16x8 a = *(bf16x8*)&as[(li * 64 + ka) ^ ((li & 7) << 3)];
    #pragma unroll
    for (int nb = 0; nb < 2; ++nb) {
      int bc = wave * 32 + nb * 16 + li;
      bf16x8 b = *(bf16x8*)&bs[(bc * 64 + ka) ^ ((bc & 7) << 3)];
      acc[nb] = __builtin_amdgcn_mfma_f32_16x16x32_bf16(a, b, acc[nb], 0, 0, 0);
    }
  }

  const int orow = n0 + (lane >> 4) * 4;
  if (wave < 2) {                             // cols 0..63 = rel -> hW (fp8)
    #pragma unroll
    for (int nb = 0; nb < 2; ++nb) {
      int col = wave * 32 + nb * 16 + li;
      unsigned char cb[4];
      fp8pair(acc[nb][0], acc[nb][1], cb[0], cb[1]);
      fp8pair(acc[nb][2], acc[nb][3], cb[2], cb[3]);
      #pragma unroll
      for (int rr = 0; rr < 4; ++rr)
        hW[(size_t)(orow + rr) * 64 + col] = cb[rr];
    }
  } else {                                    // cols 64..127 = root -> bf16 (+bias)
    #pragma unroll
    for (int nb = 0; nb < 2; ++nb) {
      int col = (wave - 2) * 32 + nb * 16 + li;
      float bb = brel[col];
      #pragma unroll
      for (int rr = 0; rr < 4; ++rr)
        rootOut[(size_t)(orow + rr) * 64 + col] = f2bf(acc[nb][rr] + bb);
    }
  }
}

// ------ final gather: h3 = relu(root3 + G(hW3)), bf16 out ------
__global__ __launch_bounds__(256) void agg_final_kernel(
    const unsigned short* __restrict__ rootPrev,
    const unsigned char* __restrict__ hWp,
    const int* __restrict__ rs, const int* __restrict__ ren,
    const int* __restrict__ ssrc,
    unsigned short* __restrict__ h3) {
  int tid = blockIdx.x * 256 + threadIdx.x;
  int node = tid >> 4, c4 = (tid & 15) * 4;   // grid sized exactly -> no guard
  const int s0 = rs[node], s1 = ren[node];
  ushort4 rt = *(const ushort4*)&rootPrev[(size_t)node * 64 + c4];
  float4 a0 = make_float4(bf2f(rt.x), bf2f(rt.y), bf2f(rt.z), bf2f(rt.w));
  float4 a1 = make_float4(0.f, 0.f, 0.f, 0.f);
  int e = s0;
  for (; e + 2 <= s1; e += 2) {
    int sA = ssrc[e], sB = ssrc[e + 1];
    unsigned uA = *(const unsigned*)&hWp[(size_t)sA * 64 + c4];
    unsigned uB = *(const unsigned*)&hWp[(size_t)sB * 64 + c4];
    float4 vA = fp8x4_dec(uA), vB = fp8x4_dec(uB);
    a0.x += vA.x; a0.y += vA.y; a0.z += vA.z; a0.w += vA.w;
    a1.x += vB.x; a1.y += vB.y; a1.z += vB.z; a1.w += vB.w;
  }
  if (e < s1) {
    unsigned uA = *(const unsigned*)&hWp[(size_t)ssrc[e] * 64 + c4];
    float4 vA = fp8x4_dec(uA);
    a0.x += vA.x; a0.y += vA.y; a0.z += vA.z; a0.w += vA.w;
  }
  ushort4 o;
  o.x = f2bf(fmaxf(a0.x + a1.x, 0.f)); o.y = f2bf(fmaxf(a0.y + a1.y, 0.f));
  o.z = f2bf(fmaxf(a0.z + a1.z, 0.f)); o.w = f2bf(fmaxf(a0.w + a1.w, 0.f));
  *(ushort4*)&h3[(size_t)node * 64 + c4] = o;
}

// ------- mean-pool + MLP head: one block per graph -------
__global__ __launch_bounds__(256) void pool_head_kernel(
    const unsigned short* __restrict__ buf,   // [NN][64] bf16 (h3, already relu'd)
    const int* __restrict__ gstart,
    const float* __restrict__ Wfc1, const float* __restrict__ bfc1,
    const float* __restrict__ Wfc2, const float* __restrict__ bfc2,
    float* __restrict__ out) {
  __shared__ float ps[16][64];
  __shared__ float m[64];
  __shared__ float h1[32];
  const int g = blockIdx.x, t = threadIdx.x;
  const int grp = t >> 4, l16 = t & 15;
  const int s0 = gstart[g], s1 = gstart[g + 1];
  float4 acc = make_float4(0.f, 0.f, 0.f, 0.f);
  for (int i = s0 + grp; i < s1; i += 16) {
    ushort4 u = *(const ushort4*)&buf[(size_t)i * 64 + l16 * 4];
    acc.x += bf2f(u.x); acc.y += bf2f(u.y);
    acc.z += bf2f(u.z); acc.w += bf2f(u.w);
  }
  *(float4*)&ps[grp][l16 * 4] = acc;
  __syncthreads();
  if (t < 64) {
    float s = 0.f;
    #pragma unroll
    for (int p = 0; p < 16; ++p) s += ps[p][t];
    m[t] = s / fmaxf((float)(s1 - s0), 1.0f);
  }
  __syncthreads();
  if (t < 32) {
    float a = bfc1[t];
    #pragma unroll
    for (int k = 0; k < 64; ++k) a += m[k] * Wfc1[k * 32 + t];
    h1[t] = fmaxf(a, 0.f);
  }
  __syncthreads();
  if (t == 0) {
    float o = bfc2[0];
    #pragma unroll
    for (int j = 0; j < 32; ++j) o += h1[j] * Wfc2[j];
    out[g] = o;
  }
}

extern "C" void kernel_launch(void* const* d_in, const int* in_sizes, int n_in,
                              void* d_out, int out_size, void* d_ws, size_t ws_size,
                              hipStream_t stream) {
  const float* x      = (const float*)d_in[0];
  const int*   ei     = (const int*)d_in[1];
  const int*   batch  = (const int*)d_in[2];
  const float* Wrel1  = (const float*)d_in[3];
  const float* brel1  = (const float*)d_in[4];
  const float* Wroot1 = (const float*)d_in[5];
  const float* Wrel2  = (const float*)d_in[6];
  const float* brel2  = (const float*)d_in[7];
  const float* Wroot2 = (const float*)d_in[8];
  const float* Wrel3  = (const float*)d_in[9];
  const float* brel3  = (const float*)d_in[10];
  const float* Wroot3 = (const float*)d_in[11];
  const float* Wfc1   = (const float*)d_in[12];
  const float* bfc1   = (const float*)d_in[13];
  const float* Wfc2   = (const float*)d_in[14];
  const float* bfc2   = (const float*)d_in[15];
  const int* src = ei;
  const int* dst = ei + NE;

  char* w = (char*)d_ws;
  auto alloc = [&](size_t bytes) -> char* {
    char* p = w; w += (bytes + 255) & ~(size_t)255; return p;
  };
  unsigned char*  hWa   = (unsigned char*)alloc((size_t)NN * 64);       // fp8
  unsigned char*  hWb   = (unsigned char*)alloc((size_t)NN * 64);       // fp8
  unsigned short* rootA = (unsigned short*)alloc((size_t)NN * 64 * 2);  // bf16
  unsigned short* rootB = (unsigned short*)alloc((size_t)NN * 64 * 2);  // bf16
  int*   rs     = (int*)alloc((size_t)NBK * 64 * 4);
  int*   ren    = (int*)alloc((size_t)NBK * 64 * 4);
  int*   ssrc   = (int*)alloc((size_t)NBK * CAP * 4);
  int*   gstart = (int*)alloc((size_t)(GRAPHS + 1) * 4);
  int*   bcnt   = (int*)alloc((size_t)NBK * 4);
  unsigned* ebuf = (unsigned*)alloc((size_t)NBK * CAP * 4);
  unsigned short* Wt1 = (unsigned short*)alloc((size_t)128 * 128 * 2);
  unsigned short* Wt2 = (unsigned short*)alloc((size_t)128 * 64 * 2);
  unsigned short* Wt3 = (unsigned short*)alloc((size_t)128 * 64 * 2);

  setup_kernel<<<64, 256, 0, stream>>>(batch, gstart, bcnt,
                                       Wrel1, Wroot1, Wrel2, Wroot2, Wrel3, Wroot3,
                                       Wt1, Wt2, Wt3);
  // merged: gemm_l1 (blocks 0..781) + bin (blocks 782..977)
  bin_gemm1_kernel<<<GG1 + (NE + 4095) / 4096, 256, 0, stream>>>(
      x, Wt1, brel1, hWa, rootA, src, dst, bcnt, ebuf);
  bucket_csr_kernel<<<NBK, 256, 0, stream>>>(ebuf, bcnt, rs, ren, ssrc);

  // layer 2: a2 = relu(rootA + G(hWa)); hWb = a2@Wrel2, rootB = a2@Wroot2 + b2
  agg_gemm_kernel<<<NN / 16, 256, 0, stream>>>(rootA, hWa, rs, ren, ssrc,
                                               Wt2, brel2, hWb, rootB);
  // layer 3: a3 = relu(rootB + G(hWb)); hWa = a3@Wrel3, rootA = a3@Wroot3 + b3
  agg_gemm_kernel<<<NN / 16, 256, 0, stream>>>(rootB, hWb, rs, ren, ssrc,
                                               Wt3, brel3, hWa, rootA);
  // h3 = relu(rootA + G(hWa)) -> rootB
  agg_final_kernel<<<(NN * 16) / 256, 256, 0, stream>>>(rootA, hWa, rs, ren, ssrc,
                                                        rootB);
  pool_head_kernel<<<GRAPHS, 256, 0, stream>>>(rootB, gstart, Wfc1, bfc1, Wfc2, bfc2,
                                               (float*)d_out);
}